// Round 10
// baseline (747.752 us; speedup 1.0000x reference)
//
#include <hip/hip_runtime.h>
#include <hip/hip_bf16.h>

#define GN 50000
#define GE 600000
#define DD 128
#define TQ 4096          // RBF table quantization (4097 rows per layer)
#define NBOND 2268       // 12*27*7 bond combo rows
#define TROWS (2*(TQ+1) + NBOND)   // table-build blocks per layer
#define SCB 49           // scan blocks of 1024 -> 49*1024 = 50176 >= GN+1
#define NBANK 16         // stats banks: 49 contenders/addr (fine per R6 evidence)
#define SSET (NBANK*256) // floats per stats set: [bank][0..127 sum | 128..255 sumsq]
#define NB 782           // (GN+63)/64 row tiles
#define NB4 (NB*4)       // N-split x4 gemm grid: 64 rows x 32 cols per block
                         // (R9: 782 blocks = 3.05 waves/SIMD -> latency-bound B-frag loads;
                         //  x4 blocks = 12.2 waves/SIMD for latency hiding)

typedef __attribute__((ext_vector_type(8))) short short8;
typedef __attribute__((ext_vector_type(4))) float floatx4;

__device__ __forceinline__ unsigned short f2b(float f) {
    __hip_bfloat16 h = __float2bfloat16(f);
    return __builtin_bit_cast(unsigned short, h);
}
__device__ __forceinline__ float b2f_lo(unsigned int u) { return __uint_as_float(u << 16); }
__device__ __forceinline__ float b2f_hi(unsigned int u) { return __uint_as_float(u & 0xffff0000u); }
__device__ __forceinline__ float bs2f(short s) {
    return __uint_as_float(((unsigned int)(unsigned short)s) << 16);
}

// ---------------------------------------------------------------- atom encoder -> h (bf16)
__global__ __launch_bounds__(256) void atom_kernel(
    const int* __restrict__ x, const int* __restrict__ atom_off,
    const float* __restrict__ atom_emb, unsigned short* __restrict__ h)
{
    int t = blockIdx.x * 256 + threadIdx.x;
    if (t >= GN * DD) return;
    int n = t >> 7, d = t & 127;
    float s = 0.f;
#pragma unroll
    for (int f = 0; f < 9; f++) {
        int idx = x[n * 9 + f] + atom_off[f];
        s += atom_emb[idx * DD + d];
    }
    h[t] = f2b(s);
}

// ---------------------------------------------------------------- CSR build
__global__ __launch_bounds__(256) void hist_kernel(const int* __restrict__ ei, int* __restrict__ count)
{
    int e = blockIdx.x * 256 + threadIdx.x;
    if (e < GE) atomicAdd(&count[ei[GE + e]], 1);
}

__global__ __launch_bounds__(1024) void scan1_kernel(
    const int* __restrict__ count, int* __restrict__ row_start, int* __restrict__ blocksum)
{
    __shared__ int sh[1024];
    int t = threadIdx.x;
    int idx = blockIdx.x * 1024 + t;
    int v = (idx < GN) ? count[idx] : 0;
    sh[t] = v;
    __syncthreads();
    for (int off = 1; off < 1024; off <<= 1) {
        int u = (t >= off) ? sh[t - off] : 0;
        __syncthreads();
        sh[t] += u;
        __syncthreads();
    }
    if (idx <= GN) row_start[idx] = (t == 0) ? 0 : sh[t - 1];   // local exclusive
    if (t == 1023) blocksum[blockIdx.x] = sh[1023];
}

__global__ __launch_bounds__(64) void scan2_kernel(
    const int* __restrict__ blocksum, int* __restrict__ blockoff)
{
    int t = threadIdx.x;
    int v = (t < SCB) ? blocksum[t] : 0;
#pragma unroll
    for (int off = 1; off < 64; off <<= 1) {
        int u = __shfl_up(v, off);
        if (t >= off) v += u;
    }
    int e = __shfl_up(v, 1);
    if (t == 0) e = 0;
    if (t < SCB) blockoff[t] = e;
}

__global__ __launch_bounds__(1024) void scan3_kernel(
    int* __restrict__ row_start, const int* __restrict__ blockoff)
{
    int idx = blockIdx.x * 1024 + threadIdx.x;
    if (idx <= GN) row_start[idx] += blockoff[blockIdx.x];
}

// scatter + pack per-edge metadata {src, q1|q2<<16, bondcombo, 0} in CSR order
__global__ __launch_bounds__(256) void scatter_kernel(
    const int* __restrict__ ei, const int* __restrict__ eai, const float* __restrict__ eaf,
    const int* __restrict__ row_start, int* __restrict__ fill, int4* __restrict__ ep)
{
    int e = blockIdx.x * 256 + threadIdx.x;
    if (e < GE) {
        int d = ei[GE + e];
        int p = row_start[d] + atomicAdd(&fill[d], 1);
        int src = ei[e];
        float x1 = eaf[2 * e], x2 = eaf[2 * e + 1];
        int q1 = (int)(x1 * (float)TQ + 0.5f); q1 = min(max(q1, 0), TQ);
        int q2 = (int)(x2 * (float)TQ + 0.5f); q2 = min(max(q2, 0), TQ);
        int b0 = eai[3 * e], b1 = eai[3 * e + 1], b2 = eai[3 * e + 2];
        ep[p] = make_int4(src, q1 | (q2 << 16), (b0 * 27 + b1) * 7 + b2, 0);
    }
}

// ---------------------------------------------------------------- tables for ALL layers (bf16)
__global__ __launch_bounds__(128) void tables_kernel(
    const float* __restrict__ W_bl, const float* __restrict__ b_bl,
    const float* __restrict__ W_pr, const float* __restrict__ b_pr,
    const float* __restrict__ bond_emb, const int* __restrict__ bond_off,
    unsigned short* __restrict__ tbl_bl, unsigned short* __restrict__ tbl_pr,
    unsigned short* __restrict__ tbl_bond)
{
    int l = blockIdx.x / TROWS;
    int b = blockIdx.x % TROWS;
    int d = threadIdx.x;
    const float* W_bl_l = W_bl + (size_t)l * 20 * DD;
    const float* W_pr_l = W_pr + (size_t)l * 20 * DD;
    const float* bemb_l = bond_emb + (size_t)l * 46 * DD;
    if (b < (TQ + 1)) {
        float xq = b * (1.0f / TQ);
        float s = b_bl[(size_t)l * DD + d] + b_pr[(size_t)l * DD + d];
#pragma unroll
        for (int k = 0; k < 20; k++) {
            float dl = xq - 0.1f * k;
            s += __expf(-10.f * dl * dl) * W_bl_l[k * DD + d];
        }
        tbl_bl[((size_t)l * (TQ + 1) + b) * DD + d] = f2b(s);
    } else if (b < 2 * (TQ + 1)) {
        int q = b - (TQ + 1);
        float xq = q * (1.0f / TQ);
        float s = 0.f;
#pragma unroll
        for (int k = 0; k < 20; k++) {
            float dl = xq - 0.05f * k;
            s += __expf(-dl * dl) * W_pr_l[k * DD + d];
        }
        tbl_pr[((size_t)l * (TQ + 1) + q) * DD + d] = f2b(s);
    } else {
        int r = b - 2 * (TQ + 1);
        int b0 = r / 189;            // 27*7
        int rem = r % 189;
        int b1 = rem / 7, b2 = rem % 7;
        tbl_bond[((size_t)l * NBOND + r) * DD + d] =
            f2b(bemb_l[(b0 + bond_off[0]) * DD + d]
              + bemb_l[(b1 + bond_off[1]) * DD + d]
              + bemb_l[(b2 + bond_off[2]) * DD + d]);
    }
}

// ---------------------------------------------------------------- W -> MFMA B-fragment hi/lo packs
__global__ __launch_bounds__(256) void wfrag_kernel(
    const float* __restrict__ W1, const float* __restrict__ W2,
    unsigned short* __restrict__ wf_hi, unsigned short* __restrict__ wf_lo)
{
    int t = blockIdx.x * 256 + threadIdx.x;    // 0..20479
    if (t >= 10 * 2048) return;
    int mat = t >> 11;
    int rem = t & 2047;
    int kt = rem >> 9;
    int rem2 = rem & 511;
    int nt = rem2 >> 6;
    int lane = rem2 & 63;
    const float* src = (mat & 1) ? (W2 + (size_t)(mat >> 1) * DD * DD)
                                 : (W1 + (size_t)(mat >> 1) * DD * DD);
    int n = nt * 16 + (lane & 15);
    int k0 = kt * 32 + (lane >> 4) * 8;
    size_t base = (size_t)mat * 16384 + (size_t)((kt * 8 + nt) * 64 + lane) * 8;
#pragma unroll
    for (int j = 0; j < 8; j++) {
        float w = src[(size_t)(k0 + j) * DD + n];
        unsigned short hi = f2b(w);
        wf_hi[base + j] = hi;
        wf_lo[base + j] = f2b(w - bs2f((short)hi));
    }
}

// ---------------------------------------------------------------- edge/aggregate (wave per node)
// hsrc: layer0 -> atom h (identity); layer>0 -> raw z2 (bf16), bn2+relu on the fly
// A[n] (f32) = (1+eps)*h[n] + sum_{e: dst=n} relu(h[src]+e_edge)
__global__ __launch_bounds__(256) void edge_kernel(
    const int4* __restrict__ ep,
    const unsigned short* __restrict__ tbl_bl, const unsigned short* __restrict__ tbl_pr,
    const unsigned short* __restrict__ tbl_bond,
    const unsigned short* __restrict__ hsrc, const int* __restrict__ row_start,
    const float* __restrict__ eps_gin, int layer, int apply_bn,
    const float* __restrict__ stats_prev, const float* __restrict__ g_prev,
    const float* __restrict__ b_prev,
    float* __restrict__ A)
{
    __shared__ float sc_s[DD], tr_s[DD];
    int tid = threadIdx.x;
    if (tid < DD) {
        float sc = 1.f, tr = 0.f;
        if (apply_bn) {
            float s = 0.f, q = 0.f;
#pragma unroll
            for (int bk = 0; bk < NBANK; bk++) {
                s += stats_prev[bk * 256 + tid];
                q += stats_prev[bk * 256 + 128 + tid];
            }
            float m = s * (1.0f / GN);
            float v = q * (1.0f / GN) - m * m;
            sc = g_prev[tid] * rsqrtf(v + 1e-5f);
            tr = b_prev[tid] - m * sc;
        }
        sc_s[tid] = sc;
        tr_s[tid] = tr;
    }
    __syncthreads();

    int wid = __builtin_amdgcn_readfirstlane(tid >> 6);
    int lane = tid & 63;
    float sc0 = sc_s[2 * lane],     tr0 = tr_s[2 * lane];
    float sc1 = sc_s[2 * lane + 1], tr1 = tr_s[2 * lane + 1];
    float rmin = apply_bn ? 0.f : -__builtin_inff();

    int n = blockIdx.x * 4 + wid;
    int s0 = __builtin_amdgcn_readfirstlane(row_start[n]);
    int s1 = __builtin_amdgcn_readfirstlane(row_start[n + 1]);
    const unsigned int* hu = (const unsigned int*)hsrc;
    const unsigned int* tb = (const unsigned int*)tbl_bl;
    const unsigned int* tp = (const unsigned int*)tbl_pr;
    const unsigned int* tg = (const unsigned int*)tbl_bond;
    float a0 = 0.f, a1 = 0.f;
    int p = s0;
    for (; p + 2 <= s1; p += 2) {               // 2-way unroll for MLP
        int4 m0 = ep[p];
        int4 m1 = ep[p + 1];
        unsigned int ub0 = tb[(size_t)(m0.y & 0xffff) * 64 + lane];
        unsigned int up0 = tp[(size_t)((unsigned)m0.y >> 16) * 64 + lane];
        unsigned int ug0 = tg[(size_t)m0.z * 64 + lane];
        unsigned int uh0 = hu[(size_t)m0.x * 64 + lane];
        unsigned int ub1 = tb[(size_t)(m1.y & 0xffff) * 64 + lane];
        unsigned int up1 = tp[(size_t)((unsigned)m1.y >> 16) * 64 + lane];
        unsigned int ug1 = tg[(size_t)m1.z * 64 + lane];
        unsigned int uh1 = hu[(size_t)m1.x * 64 + lane];
        float h00 = fmaxf(fmaf(b2f_lo(uh0), sc0, tr0), rmin);
        float h01 = fmaxf(fmaf(b2f_hi(uh0), sc1, tr1), rmin);
        float h10 = fmaxf(fmaf(b2f_lo(uh1), sc0, tr0), rmin);
        float h11 = fmaxf(fmaf(b2f_hi(uh1), sc1, tr1), rmin);
        a0 += fmaxf(h00 + b2f_lo(ub0) + b2f_lo(up0) + b2f_lo(ug0), 0.f);
        a1 += fmaxf(h01 + b2f_hi(ub0) + b2f_hi(up0) + b2f_hi(ug0), 0.f);
        a0 += fmaxf(h10 + b2f_lo(ub1) + b2f_lo(up1) + b2f_lo(ug1), 0.f);
        a1 += fmaxf(h11 + b2f_hi(ub1) + b2f_hi(up1) + b2f_hi(ug1), 0.f);
    }
    if (p < s1) {
        int4 m0 = ep[p];
        unsigned int ub0 = tb[(size_t)(m0.y & 0xffff) * 64 + lane];
        unsigned int up0 = tp[(size_t)((unsigned)m0.y >> 16) * 64 + lane];
        unsigned int ug0 = tg[(size_t)m0.z * 64 + lane];
        unsigned int uh0 = hu[(size_t)m0.x * 64 + lane];
        float h00 = fmaxf(fmaf(b2f_lo(uh0), sc0, tr0), rmin);
        float h01 = fmaxf(fmaf(b2f_hi(uh0), sc1, tr1), rmin);
        a0 += fmaxf(h00 + b2f_lo(ub0) + b2f_lo(up0) + b2f_lo(ug0), 0.f);
        a1 += fmaxf(h01 + b2f_hi(ub0) + b2f_hi(up0) + b2f_hi(ug0), 0.f);
    }
    float eps1 = 1.f + eps_gin[layer];
    unsigned int un = hu[(size_t)n * 64 + lane];
    a0 += eps1 * fmaxf(fmaf(b2f_lo(un), sc0, tr0), rmin);
    a1 += eps1 * fmaxf(fmaf(b2f_hi(un), sc1, tr1), rmin);
    float2 o; o.x = a0; o.y = a1;
    *(float2*)(A + (size_t)n * DD + 2 * lane) = o;
}

// ---------------------------------------------------------------- MFMA GEMM1 (N-split x4): z1 = A@W1+b1
// block = 64 rows x 32 cols; grid NB4; 12.2 waves/SIMD for load-latency hiding
__global__ __launch_bounds__(256) void gemm1_kernel(
    const float* __restrict__ Asrc,
    const unsigned short* __restrict__ wf_hi, const unsigned short* __restrict__ wf_lo,
    const float* __restrict__ bias, float* __restrict__ Cdst, float* __restrict__ stats_out)
{
    __shared__ float red_s[4][32];
    __shared__ float red_q[4][32];
    int tid = threadIdx.x, wid = tid >> 6, lane = tid & 63;
    int ct = blockIdx.x & 3;             // col tile (32 cols)
    int rb = blockIdx.x >> 2;            // row block (64 rows)
    int row0 = rb * 64;
    int quad = lane >> 4, l16 = lane & 15;
    int row = row0 + wid * 16 + l16;
    bool rvalid = row < GN;

    floatx4 acc[2];
    acc[0] = (floatx4){0.f, 0.f, 0.f, 0.f};
    acc[1] = (floatx4){0.f, 0.f, 0.f, 0.f};

    const short8* bhp = (const short8*)wf_hi;
    const short8* blp = (const short8*)wf_lo;
#pragma unroll
    for (int kt = 0; kt < 4; kt++) {
        short8 ahi = {0,0,0,0,0,0,0,0}, alo = {0,0,0,0,0,0,0,0};
        if (rvalid) {
            const float* ap = Asrc + (size_t)row * DD + kt * 32 + quad * 8;
            float a[8];
            *(float4*)(a)     = *(const float4*)(ap);
            *(float4*)(a + 4) = *(const float4*)(ap + 4);
#pragma unroll
            for (int j = 0; j < 8; j++) {
                unsigned short hi = f2b(a[j]);
                ahi[j] = (short)hi;
                alo[j] = (short)f2b(a[j] - bs2f((short)hi));
            }
        }
#pragma unroll
        for (int nt = 0; nt < 2; nt++) {
            int ntg = ct * 2 + nt;
            short8 bhi = bhp[(kt * 8 + ntg) * 64 + lane];
            short8 blo = blp[(kt * 8 + ntg) * 64 + lane];
            acc[nt] = __builtin_amdgcn_mfma_f32_16x16x32_bf16(ahi, bhi, acc[nt], 0, 0, 0);
            acc[nt] = __builtin_amdgcn_mfma_f32_16x16x32_bf16(alo, bhi, acc[nt], 0, 0, 0);
            acc[nt] = __builtin_amdgcn_mfma_f32_16x16x32_bf16(ahi, blo, acc[nt], 0, 0, 0);
        }
    }

#pragma unroll
    for (int nt = 0; nt < 2; nt++) {
        int col = (ct * 2 + nt) * 16 + l16;
        float bv = bias[col];
        float s = 0.f, q = 0.f;
#pragma unroll
        for (int v = 0; v < 4; v++) {
            int r = row0 + wid * 16 + quad * 4 + v;
            float o = acc[nt][v] + bv;
            if (r < GN) {
                s += o; q += o * o;
                Cdst[(size_t)r * DD + col] = o;
            }
        }
        s += __shfl_xor(s, 16); s += __shfl_xor(s, 32);
        q += __shfl_xor(q, 16); q += __shfl_xor(q, 32);
        if (lane < 16) { red_s[wid][nt * 16 + lane] = s; red_q[wid][nt * 16 + lane] = q; }
    }
    __syncthreads();
    int bank = (blockIdx.x >> 2) & (NBANK - 1);   // row-based: 16 banks per column
    int c0 = ct * 32;
    if (tid < 32) {
        float s = red_s[0][tid] + red_s[1][tid] + red_s[2][tid] + red_s[3][tid];
        atomicAdd(&stats_out[bank * 256 + c0 + tid], s);
    } else if (tid < 64) {
        int c = tid - 32;
        float q = red_q[0][c] + red_q[1][c] + red_q[2][c] + red_q[3][c];
        atomicAdd(&stats_out[bank * 256 + 128 + c0 + c], q);
    }
}

// ---------------------------------------------------------------- MFMA GEMM2 (N-split x4): z2 = relu(bn1(z1))@W2+b2
__global__ __launch_bounds__(256) void gemm2_kernel(
    const float* __restrict__ Asrc,
    const unsigned short* __restrict__ wf_hi, const unsigned short* __restrict__ wf_lo,
    const float* __restrict__ bias,
    unsigned short* __restrict__ Cbf, float* __restrict__ Cf32, int out_bf16,
    const float* __restrict__ stats_in, const float* __restrict__ bn_g,
    const float* __restrict__ bn_b, float* __restrict__ stats_out)
{
    __shared__ float sc_s[DD], tr_s[DD];
    __shared__ float red_s[4][32];
    __shared__ float red_q[4][32];
    int tid = threadIdx.x, wid = tid >> 6, lane = tid & 63;
    if (tid < DD) {
        float s = 0.f, q = 0.f;
#pragma unroll
        for (int bk = 0; bk < NBANK; bk++) {
            s += stats_in[bk * 256 + tid];
            q += stats_in[bk * 256 + 128 + tid];
        }
        float m = s * (1.0f / GN);
        float v = q * (1.0f / GN) - m * m;
        float sc = bn_g[tid] * rsqrtf(v + 1e-5f);
        sc_s[tid] = sc;
        tr_s[tid] = bn_b[tid] - m * sc;
    }
    __syncthreads();
    int ct = blockIdx.x & 3;
    int rb = blockIdx.x >> 2;
    int row0 = rb * 64;
    int quad = lane >> 4, l16 = lane & 15;
    int row = row0 + wid * 16 + l16;
    bool rvalid = row < GN;

    floatx4 acc[2];
    acc[0] = (floatx4){0.f, 0.f, 0.f, 0.f};
    acc[1] = (floatx4){0.f, 0.f, 0.f, 0.f};

    const short8* bhp = (const short8*)wf_hi;
    const short8* blp = (const short8*)wf_lo;
#pragma unroll
    for (int kt = 0; kt < 4; kt++) {
        short8 ahi = {0,0,0,0,0,0,0,0}, alo = {0,0,0,0,0,0,0,0};
        if (rvalid) {
            const float* ap = Asrc + (size_t)row * DD + kt * 32 + quad * 8;
            float a[8];
            *(float4*)(a)     = *(const float4*)(ap);
            *(float4*)(a + 4) = *(const float4*)(ap + 4);
            int kb = kt * 32 + quad * 8;
#pragma unroll
            for (int j = 0; j < 8; j++)
                a[j] = fmaxf(a[j] * sc_s[kb + j] + tr_s[kb + j], 0.f);
#pragma unroll
            for (int j = 0; j < 8; j++) {
                unsigned short hi = f2b(a[j]);
                ahi[j] = (short)hi;
                alo[j] = (short)f2b(a[j] - bs2f((short)hi));
            }
        }
#pragma unroll
        for (int nt = 0; nt < 2; nt++) {
            int ntg = ct * 2 + nt;
            short8 bhi = bhp[(kt * 8 + ntg) * 64 + lane];
            short8 blo = blp[(kt * 8 + ntg) * 64 + lane];
            acc[nt] = __builtin_amdgcn_mfma_f32_16x16x32_bf16(ahi, bhi, acc[nt], 0, 0, 0);
            acc[nt] = __builtin_amdgcn_mfma_f32_16x16x32_bf16(alo, bhi, acc[nt], 0, 0, 0);
            acc[nt] = __builtin_amdgcn_mfma_f32_16x16x32_bf16(ahi, blo, acc[nt], 0, 0, 0);
        }
    }

#pragma unroll
    for (int nt = 0; nt < 2; nt++) {
        int col = (ct * 2 + nt) * 16 + l16;
        float bv = bias[col];
        float s = 0.f, q = 0.f;
#pragma unroll
        for (int v = 0; v < 4; v++) {
            int r = row0 + wid * 16 + quad * 4 + v;
            float o = acc[nt][v] + bv;
            if (r < GN) {
                s += o; q += o * o;
                if (out_bf16) Cbf[(size_t)r * DD + col] = f2b(o);
                else          Cf32[(size_t)r * DD + col] = o;
            }
        }
        s += __shfl_xor(s, 16); s += __shfl_xor(s, 32);
        q += __shfl_xor(q, 16); q += __shfl_xor(q, 32);
        if (lane < 16) { red_s[wid][nt * 16 + lane] = s; red_q[wid][nt * 16 + lane] = q; }
    }
    __syncthreads();
    int bank = (blockIdx.x >> 2) & (NBANK - 1);
    int c0 = ct * 32;
    if (tid < 32) {
        float s = red_s[0][tid] + red_s[1][tid] + red_s[2][tid] + red_s[3][tid];
        atomicAdd(&stats_out[bank * 256 + c0 + tid], s);
    } else if (tid < 64) {
        int c = tid - 32;
        float q = red_q[0][c] + red_q[1][c] + red_q[2][c] + red_q[3][c];
        atomicAdd(&stats_out[bank * 256 + 128 + c0 + c], q);
    }
}

// ---------------------------------------------------------------- BN2 apply, layer 4 only (f32 out)
__global__ __launch_bounds__(256) void bn_apply_kernel(
    const float* __restrict__ Z, const float* __restrict__ stats2,
    const float* __restrict__ g, const float* __restrict__ b,
    float* __restrict__ fout)
{
    __shared__ float sc_s[DD], tr_s[DD];
    int tid = threadIdx.x;
    if (tid < DD) {
        float s = 0.f, q = 0.f;
#pragma unroll
        for (int bk = 0; bk < NBANK; bk++) {
            s += stats2[bk * 256 + tid];
            q += stats2[bk * 256 + 128 + tid];
        }
        float m = s * (1.0f / GN);
        float v = q * (1.0f / GN) - m * m;
        float sc = g[tid] * rsqrtf(v + 1e-5f);
        sc_s[tid] = sc;
        tr_s[tid] = b[tid] - m * sc;
    }
    __syncthreads();
    const int total = GN * DD;
    for (int t = blockIdx.x * 256 + tid; t < total; t += gridDim.x * 256) {
        int c = t & 127;
        fout[t] = Z[t] * sc_s[c] + tr_s[c];
    }
}

// ---------------------------------------------------------------- host launcher
extern "C" void kernel_launch(void* const* d_in, const int* in_sizes, int n_in,
                              void* d_out, int out_size, void* d_ws, size_t ws_size,
                              hipStream_t stream)
{
    const int*   x        = (const int*)d_in[0];
    const int*   ei       = (const int*)d_in[1];
    const int*   eai      = (const int*)d_in[2];
    const float* eaf      = (const float*)d_in[3];
    const int*   atom_off = (const int*)d_in[4];
    const int*   bond_off = (const int*)d_in[5];
    const float* atom_emb = (const float*)d_in[6];
    const float* bond_emb = (const float*)d_in[7];
    const float* W_bl     = (const float*)d_in[8];
    const float* b_bl     = (const float*)d_in[9];
    const float* W_pr     = (const float*)d_in[10];
    const float* b_pr     = (const float*)d_in[11];
    const float* W1       = (const float*)d_in[12];
    const float* b1       = (const float*)d_in[13];
    const float* bn1g     = (const float*)d_in[14];
    const float* bn1b     = (const float*)d_in[15];
    const float* W2       = (const float*)d_in[16];
    const float* b2       = (const float*)d_in[17];
    const float* eps_gin  = (const float*)d_in[18];
    const float* bng      = (const float*)d_in[19];
    const float* bnb      = (const float*)d_in[20];
    float* out = (float*)d_out;

    char* p = (char*)d_ws;
    unsigned short* h_bf  = (unsigned short*)p;  p += (size_t)GN * DD * 2;   // atom output (layer 0)
    unsigned short* z2_bf = (unsigned short*)p;  p += (size_t)GN * DD * 2;   // raw z2 (layers 0-3)
    float* A              = (float*)p;           p += (size_t)GN * DD * 4;   // edge output
    float* z1             = (float*)p;           p += (size_t)GN * DD * 4;
    float* z2f            = (float*)p;           p += (size_t)GN * DD * 4;   // f32 z2 (layer 4)
    unsigned short* tbl_bl   = (unsigned short*)p;  p += (size_t)5 * (TQ + 1) * DD * 2;
    unsigned short* tbl_pr   = (unsigned short*)p;  p += (size_t)5 * (TQ + 1) * DD * 2;
    unsigned short* tbl_bond = (unsigned short*)p;  p += (size_t)5 * NBOND * DD * 2;
    unsigned short* wf_hi    = (unsigned short*)p;  p += (size_t)10 * 16384 * 2;
    unsigned short* wf_lo    = (unsigned short*)p;  p += (size_t)10 * 16384 * 2;
    float* stats_all = (float*)p;  p += (size_t)10 * SSET * 4;   // [layer][{1,2}][bank][256]
    int* count    = (int*)p;    p += (size_t)GN * 4;
    int* fill     = (int*)p;    p += (size_t)GN * 4;
    int* row_start= (int*)p;    p += (size_t)(GN + 1) * 4;
    int* blocksum = (int*)p;    p += (size_t)SCB * 4;
    int* blockoff = (int*)p;    p += (size_t)SCB * 4;
    p = (char*)(((size_t)p + 15) & ~(size_t)15);
    int4* ep      = (int4*)p;   p += (size_t)GE * 16;

    hipMemsetAsync(count, 0, (size_t)GN * 4, stream);
    hipMemsetAsync(fill,  0, (size_t)GN * 4, stream);
    hipMemsetAsync(stats_all, 0, (size_t)10 * SSET * 4, stream);

    hist_kernel<<<(GE + 255) / 256, 256, 0, stream>>>(ei, count);
    scan1_kernel<<<SCB, 1024, 0, stream>>>(count, row_start, blocksum);
    scan2_kernel<<<1, 64, 0, stream>>>(blocksum, blockoff);
    scan3_kernel<<<SCB, 1024, 0, stream>>>(row_start, blockoff);
    scatter_kernel<<<(GE + 255) / 256, 256, 0, stream>>>(ei, eai, eaf, row_start, fill, ep);
    atom_kernel<<<(GN * DD + 255) / 256, 256, 0, stream>>>(x, atom_off, atom_emb, h_bf);
    wfrag_kernel<<<80, 256, 0, stream>>>(W1, W2, wf_hi, wf_lo);
    tables_kernel<<<5 * TROWS, 128, 0, stream>>>(
        W_bl, b_bl, W_pr, b_pr, bond_emb, bond_off, tbl_bl, tbl_pr, tbl_bond);

    for (int l = 0; l < 5; l++) {
        float* stats1 = stats_all + (size_t)(2 * l + 0) * SSET;
        float* stats2 = stats_all + (size_t)(2 * l + 1) * SSET;
        float* stats2_prev = stats_all + (size_t)(2 * (l - 1) + 1) * SSET;

        // layer 0: hsrc = atom h (identity); layers 1-4: hsrc = raw z2 of l-1, bn2+relu on the fly
        edge_kernel<<<GN / 4, 256, 0, stream>>>(
            ep,
            tbl_bl + (size_t)l * (TQ + 1) * DD,
            tbl_pr + (size_t)l * (TQ + 1) * DD,
            tbl_bond + (size_t)l * NBOND * DD,
            (l == 0) ? h_bf : z2_bf, row_start, eps_gin, l,
            (l > 0) ? 1 : 0,
            (l > 0) ? stats2_prev : stats_all,          // unused when apply_bn=0
            bng + (size_t)(l > 0 ? l - 1 : 0) * DD,
            bnb + (size_t)(l > 0 ? l - 1 : 0) * DD,
            A);

        gemm1_kernel<<<NB4, 256, 0, stream>>>(
            A, wf_hi + (size_t)(l * 2 + 0) * 16384, wf_lo + (size_t)(l * 2 + 0) * 16384,
            b1 + (size_t)l * DD, z1, stats1);

        gemm2_kernel<<<NB4, 256, 0, stream>>>(
            z1, wf_hi + (size_t)(l * 2 + 1) * 16384, wf_lo + (size_t)(l * 2 + 1) * 16384,
            b2 + (size_t)l * DD,
            z2_bf, z2f, (l < 4) ? 1 : 0,
            stats1, bn1g + (size_t)l * DD, bn1b + (size_t)l * DD, stats2);
    }

    bn_apply_kernel<<<1024, 256, 0, stream>>>(
        z2f, stats_all + (size_t)9 * SSET, bng + (size_t)4 * DD, bnb + (size_t)4 * DD, out);
}

// Round 11
// 692.738 us; speedup vs baseline: 1.0794x; 1.0794x over previous
//
#include <hip/hip_runtime.h>
#include <hip/hip_bf16.h>

#define GN 50000
#define GE 600000
#define DD 128
#define TQ 4096          // RBF table quantization (4097 rows per layer)
#define NBOND 2268       // 12*27*7 bond combo rows
#define TROWS (2*(TQ+1) + NBOND)   // table-build blocks per layer
#define SCB 49           // scan blocks of 1024 -> 49*1024 = 50176 >= GN+1
#define NBANK 16         // stats banks
#define SSET (NBANK*256) // floats per stats set: [bank][0..127 sum | 128..255 sumsq]
#define NB 782           // (GN+63)/64 row tiles
#define LDA2 132         // LDS A-tile stride: 128+4 -> rows alias 2-way only (free, m136)

typedef __attribute__((ext_vector_type(8))) short short8;
typedef __attribute__((ext_vector_type(4))) float floatx4;

__device__ __forceinline__ unsigned short f2b(float f) {
    __hip_bfloat16 h = __float2bfloat16(f);
    return __builtin_bit_cast(unsigned short, h);
}
__device__ __forceinline__ float b2f_lo(unsigned int u) { return __uint_as_float(u << 16); }
__device__ __forceinline__ float b2f_hi(unsigned int u) { return __uint_as_float(u & 0xffff0000u); }
__device__ __forceinline__ float bs2f(short s) {
    return __uint_as_float(((unsigned int)(unsigned short)s) << 16);
}

// ---------------------------------------------------------------- atom encoder -> h (bf16)
__global__ __launch_bounds__(256) void atom_kernel(
    const int* __restrict__ x, const int* __restrict__ atom_off,
    const float* __restrict__ atom_emb, unsigned short* __restrict__ h)
{
    int t = blockIdx.x * 256 + threadIdx.x;
    if (t >= GN * DD) return;
    int n = t >> 7, d = t & 127;
    float s = 0.f;
#pragma unroll
    for (int f = 0; f < 9; f++) {
        int idx = x[n * 9 + f] + atom_off[f];
        s += atom_emb[idx * DD + d];
    }
    h[t] = f2b(s);
}

// ---------------------------------------------------------------- CSR build
__global__ __launch_bounds__(256) void hist_kernel(const int* __restrict__ ei, int* __restrict__ count)
{
    int e = blockIdx.x * 256 + threadIdx.x;
    if (e < GE) atomicAdd(&count[ei[GE + e]], 1);
}

__global__ __launch_bounds__(1024) void scan1_kernel(
    const int* __restrict__ count, int* __restrict__ row_start, int* __restrict__ blocksum)
{
    __shared__ int sh[1024];
    int t = threadIdx.x;
    int idx = blockIdx.x * 1024 + t;
    int v = (idx < GN) ? count[idx] : 0;
    sh[t] = v;
    __syncthreads();
    for (int off = 1; off < 1024; off <<= 1) {
        int u = (t >= off) ? sh[t - off] : 0;
        __syncthreads();
        sh[t] += u;
        __syncthreads();
    }
    if (idx <= GN) row_start[idx] = (t == 0) ? 0 : sh[t - 1];   // local exclusive
    if (t == 1023) blocksum[blockIdx.x] = sh[1023];
}

__global__ __launch_bounds__(64) void scan2_kernel(
    const int* __restrict__ blocksum, int* __restrict__ blockoff)
{
    int t = threadIdx.x;
    int v = (t < SCB) ? blocksum[t] : 0;
#pragma unroll
    for (int off = 1; off < 64; off <<= 1) {
        int u = __shfl_up(v, off);
        if (t >= off) v += u;
    }
    int e = __shfl_up(v, 1);
    if (t == 0) e = 0;
    if (t < SCB) blockoff[t] = e;
}

__global__ __launch_bounds__(1024) void scan3_kernel(
    int* __restrict__ row_start, const int* __restrict__ blockoff)
{
    int idx = blockIdx.x * 1024 + threadIdx.x;
    if (idx <= GN) row_start[idx] += blockoff[blockIdx.x];
}

// scatter + pack per-edge metadata {src, q1|q2<<16, bondcombo, 0} in CSR order
__global__ __launch_bounds__(256) void scatter_kernel(
    const int* __restrict__ ei, const int* __restrict__ eai, const float* __restrict__ eaf,
    const int* __restrict__ row_start, int* __restrict__ fill, int4* __restrict__ ep)
{
    int e = blockIdx.x * 256 + threadIdx.x;
    if (e < GE) {
        int d = ei[GE + e];
        int p = row_start[d] + atomicAdd(&fill[d], 1);
        int src = ei[e];
        float x1 = eaf[2 * e], x2 = eaf[2 * e + 1];
        int q1 = (int)(x1 * (float)TQ + 0.5f); q1 = min(max(q1, 0), TQ);
        int q2 = (int)(x2 * (float)TQ + 0.5f); q2 = min(max(q2, 0), TQ);
        int b0 = eai[3 * e], b1 = eai[3 * e + 1], b2 = eai[3 * e + 2];
        ep[p] = make_int4(src, q1 | (q2 << 16), (b0 * 27 + b1) * 7 + b2, 0);
    }
}

// ---------------------------------------------------------------- tables for ALL layers (bf16)
__global__ __launch_bounds__(128) void tables_kernel(
    const float* __restrict__ W_bl, const float* __restrict__ b_bl,
    const float* __restrict__ W_pr, const float* __restrict__ b_pr,
    const float* __restrict__ bond_emb, const int* __restrict__ bond_off,
    unsigned short* __restrict__ tbl_bl, unsigned short* __restrict__ tbl_pr,
    unsigned short* __restrict__ tbl_bond)
{
    int l = blockIdx.x / TROWS;
    int b = blockIdx.x % TROWS;
    int d = threadIdx.x;
    const float* W_bl_l = W_bl + (size_t)l * 20 * DD;
    const float* W_pr_l = W_pr + (size_t)l * 20 * DD;
    const float* bemb_l = bond_emb + (size_t)l * 46 * DD;
    if (b < (TQ + 1)) {
        float xq = b * (1.0f / TQ);
        float s = b_bl[(size_t)l * DD + d] + b_pr[(size_t)l * DD + d];
#pragma unroll
        for (int k = 0; k < 20; k++) {
            float dl = xq - 0.1f * k;
            s += __expf(-10.f * dl * dl) * W_bl_l[k * DD + d];
        }
        tbl_bl[((size_t)l * (TQ + 1) + b) * DD + d] = f2b(s);
    } else if (b < 2 * (TQ + 1)) {
        int q = b - (TQ + 1);
        float xq = q * (1.0f / TQ);
        float s = 0.f;
#pragma unroll
        for (int k = 0; k < 20; k++) {
            float dl = xq - 0.05f * k;
            s += __expf(-dl * dl) * W_pr_l[k * DD + d];
        }
        tbl_pr[((size_t)l * (TQ + 1) + q) * DD + d] = f2b(s);
    } else {
        int r = b - 2 * (TQ + 1);
        int b0 = r / 189;            // 27*7
        int rem = r % 189;
        int b1 = rem / 7, b2 = rem % 7;
        tbl_bond[((size_t)l * NBOND + r) * DD + d] =
            f2b(bemb_l[(b0 + bond_off[0]) * DD + d]
              + bemb_l[(b1 + bond_off[1]) * DD + d]
              + bemb_l[(b2 + bond_off[2]) * DD + d]);
    }
}

// ---------------------------------------------------------------- W -> MFMA B-fragment hi/lo packs
__global__ __launch_bounds__(256) void wfrag_kernel(
    const float* __restrict__ W1, const float* __restrict__ W2,
    unsigned short* __restrict__ wf_hi, unsigned short* __restrict__ wf_lo)
{
    int t = blockIdx.x * 256 + threadIdx.x;    // 0..20479
    if (t >= 10 * 2048) return;
    int mat = t >> 11;
    int rem = t & 2047;
    int kt = rem >> 9;
    int rem2 = rem & 511;
    int nt = rem2 >> 6;
    int lane = rem2 & 63;
    const float* src = (mat & 1) ? (W2 + (size_t)(mat >> 1) * DD * DD)
                                 : (W1 + (size_t)(mat >> 1) * DD * DD);
    int n = nt * 16 + (lane & 15);
    int k0 = kt * 32 + (lane >> 4) * 8;
    size_t base = (size_t)mat * 16384 + (size_t)((kt * 8 + nt) * 64 + lane) * 8;
#pragma unroll
    for (int j = 0; j < 8; j++) {
        float w = src[(size_t)(k0 + j) * DD + n];
        unsigned short hi = f2b(w);
        wf_hi[base + j] = hi;
        wf_lo[base + j] = f2b(w - bs2f((short)hi));
    }
}

// ---------------------------------------------------------------- edge/aggregate (wave per node)
// hsrc: layer0 -> atom h (identity); layer>0 -> raw z2 (bf16), bn2+relu on the fly
// A[n] (f32) = (1+eps)*h[n] + sum_{e: dst=n} relu(h[src]+e_edge)
__global__ __launch_bounds__(256) void edge_kernel(
    const int4* __restrict__ ep,
    const unsigned short* __restrict__ tbl_bl, const unsigned short* __restrict__ tbl_pr,
    const unsigned short* __restrict__ tbl_bond,
    const unsigned short* __restrict__ hsrc, const int* __restrict__ row_start,
    const float* __restrict__ eps_gin, int layer, int apply_bn,
    const float* __restrict__ stats_prev, const float* __restrict__ g_prev,
    const float* __restrict__ b_prev,
    float* __restrict__ A)
{
    __shared__ float sc_s[DD], tr_s[DD];
    int tid = threadIdx.x;
    if (tid < DD) {
        float sc = 1.f, tr = 0.f;
        if (apply_bn) {
            float s = 0.f, q = 0.f;
#pragma unroll
            for (int bk = 0; bk < NBANK; bk++) {
                s += stats_prev[bk * 256 + tid];
                q += stats_prev[bk * 256 + 128 + tid];
            }
            float m = s * (1.0f / GN);
            float v = q * (1.0f / GN) - m * m;
            sc = g_prev[tid] * rsqrtf(v + 1e-5f);
            tr = b_prev[tid] - m * sc;
        }
        sc_s[tid] = sc;
        tr_s[tid] = tr;
    }
    __syncthreads();

    int wid = __builtin_amdgcn_readfirstlane(tid >> 6);
    int lane = tid & 63;
    float sc0 = sc_s[2 * lane],     tr0 = tr_s[2 * lane];
    float sc1 = sc_s[2 * lane + 1], tr1 = tr_s[2 * lane + 1];
    float rmin = apply_bn ? 0.f : -__builtin_inff();

    int n = blockIdx.x * 4 + wid;
    int s0 = __builtin_amdgcn_readfirstlane(row_start[n]);
    int s1 = __builtin_amdgcn_readfirstlane(row_start[n + 1]);
    const unsigned int* hu = (const unsigned int*)hsrc;
    const unsigned int* tb = (const unsigned int*)tbl_bl;
    const unsigned int* tp = (const unsigned int*)tbl_pr;
    const unsigned int* tg = (const unsigned int*)tbl_bond;
    float a0 = 0.f, a1 = 0.f;
    int p = s0;
    for (; p + 2 <= s1; p += 2) {               // 2-way unroll for MLP
        int4 m0 = ep[p];
        int4 m1 = ep[p + 1];
        unsigned int ub0 = tb[(size_t)(m0.y & 0xffff) * 64 + lane];
        unsigned int up0 = tp[(size_t)((unsigned)m0.y >> 16) * 64 + lane];
        unsigned int ug0 = tg[(size_t)m0.z * 64 + lane];
        unsigned int uh0 = hu[(size_t)m0.x * 64 + lane];
        unsigned int ub1 = tb[(size_t)(m1.y & 0xffff) * 64 + lane];
        unsigned int up1 = tp[(size_t)((unsigned)m1.y >> 16) * 64 + lane];
        unsigned int ug1 = tg[(size_t)m1.z * 64 + lane];
        unsigned int uh1 = hu[(size_t)m1.x * 64 + lane];
        float h00 = fmaxf(fmaf(b2f_lo(uh0), sc0, tr0), rmin);
        float h01 = fmaxf(fmaf(b2f_hi(uh0), sc1, tr1), rmin);
        float h10 = fmaxf(fmaf(b2f_lo(uh1), sc0, tr0), rmin);
        float h11 = fmaxf(fmaf(b2f_hi(uh1), sc1, tr1), rmin);
        a0 += fmaxf(h00 + b2f_lo(ub0) + b2f_lo(up0) + b2f_lo(ug0), 0.f);
        a1 += fmaxf(h01 + b2f_hi(ub0) + b2f_hi(up0) + b2f_hi(ug0), 0.f);
        a0 += fmaxf(h10 + b2f_lo(ub1) + b2f_lo(up1) + b2f_lo(ug1), 0.f);
        a1 += fmaxf(h11 + b2f_hi(ub1) + b2f_hi(up1) + b2f_hi(ug1), 0.f);
    }
    if (p < s1) {
        int4 m0 = ep[p];
        unsigned int ub0 = tb[(size_t)(m0.y & 0xffff) * 64 + lane];
        unsigned int up0 = tp[(size_t)((unsigned)m0.y >> 16) * 64 + lane];
        unsigned int ug0 = tg[(size_t)m0.z * 64 + lane];
        unsigned int uh0 = hu[(size_t)m0.x * 64 + lane];
        float h00 = fmaxf(fmaf(b2f_lo(uh0), sc0, tr0), rmin);
        float h01 = fmaxf(fmaf(b2f_hi(uh0), sc1, tr1), rmin);
        a0 += fmaxf(h00 + b2f_lo(ub0) + b2f_lo(up0) + b2f_lo(ug0), 0.f);
        a1 += fmaxf(h01 + b2f_hi(ub0) + b2f_hi(up0) + b2f_hi(ug0), 0.f);
    }
    float eps1 = 1.f + eps_gin[layer];
    unsigned int un = hu[(size_t)n * 64 + lane];
    a0 += eps1 * fmaxf(fmaf(b2f_lo(un), sc0, tr0), rmin);
    a1 += eps1 * fmaxf(fmaf(b2f_hi(un), sc1, tr1), rmin);
    float2 o; o.x = a0; o.y = a1;
    *(float2*)(A + (size_t)n * DD + 2 * lane) = o;
}

// ---------------------------------------------------------------- MFMA GEMM, canonical staging
// 64x128 tile, 782 blocks. A staged in LDS (coalesced float4 loads; stride 132 kills
// bank conflicts to 2-way). Wave w owns cols [32w,32w+32) -> wf streamed 16KB/wave
// (no per-wave duplication of the full 64KB pack). Stats: wave-owned cols -> banked atomics.
// MODE 0: C=A@W+b (f32 out). MODE 1: C=relu(bn1(A))@W+b (bf16 out if out_bf16).
template <int MODE>
__global__ __launch_bounds__(256) void gemm_kernel(
    const float* __restrict__ Asrc,
    const unsigned short* __restrict__ wf_hi, const unsigned short* __restrict__ wf_lo,
    const float* __restrict__ bias,
    unsigned short* __restrict__ Cbf, float* __restrict__ Cf32, int out_bf16,
    const float* __restrict__ stats_in, const float* __restrict__ bn_g,
    const float* __restrict__ bn_b, float* __restrict__ stats_out)
{
    __shared__ float At[64 * LDA2];    // 33.8 KB
    __shared__ float sc_s[DD], tr_s[DD];
    int tid = threadIdx.x, wid = tid >> 6, lane = tid & 63;
    int row0 = blockIdx.x * 64;

    if (MODE == 1) {
        if (tid < DD) {
            float s = 0.f, q = 0.f;
#pragma unroll
            for (int bk = 0; bk < NBANK; bk++) {
                s += stats_in[bk * 256 + tid];
                q += stats_in[bk * 256 + 128 + tid];
            }
            float m = s * (1.0f / GN);
            float v = q * (1.0f / GN) - m * m;
            float sc = bn_g[tid] * rsqrtf(v + 1e-5f);
            sc_s[tid] = sc;
            tr_s[tid] = bn_b[tid] - m * sc;
        }
    }

    // stage A tile: 8192 floats, coalesced (16 lanes = 1 cacheline, vs 32 lines/inst before)
    {
        const float* g = Asrc + (size_t)row0 * DD;   // OOB rows (last block) read into ws padding; masked later
#pragma unroll
        for (int i = 0; i < 8; i++) {
            int idx = i * 1024 + tid * 4;            // float index in row-major tile
            float4 v = *(const float4*)(g + idx);
            int r = idx >> 7, c = idx & 127;
            *(float4*)(At + r * LDA2 + c) = v;
        }
    }
    __syncthreads();

    int quad = lane >> 4, l16 = lane & 15;
    floatx4 acc[4][2];
#pragma unroll
    for (int rt = 0; rt < 4; rt++)
#pragma unroll
        for (int nt = 0; nt < 2; nt++) acc[rt][nt] = (floatx4){0.f, 0.f, 0.f, 0.f};

    const short8* bhp = (const short8*)wf_hi;
    const short8* blp = (const short8*)wf_lo;
#pragma unroll
    for (int kt = 0; kt < 4; kt++) {
        short8 ahi[4], alo[4];
        int kb = kt * 32 + quad * 8;
#pragma unroll
        for (int rt = 0; rt < 4; rt++) {
            const float* ap = At + (rt * 16 + l16) * LDA2 + kb;
            float a[8];
            *(float4*)(a)     = *(const float4*)(ap);
            *(float4*)(a + 4) = *(const float4*)(ap + 4);
            if (MODE == 1) {
#pragma unroll
                for (int j = 0; j < 8; j++)
                    a[j] = fmaxf(a[j] * sc_s[kb + j] + tr_s[kb + j], 0.f);
            }
#pragma unroll
            for (int j = 0; j < 8; j++) {
                unsigned short hi = f2b(a[j]);
                ahi[rt][j] = (short)hi;
                alo[rt][j] = (short)f2b(a[j] - bs2f((short)hi));
            }
        }
#pragma unroll
        for (int nt = 0; nt < 2; nt++) {
            int ntg = wid * 2 + nt;
            short8 bhi = bhp[(kt * 8 + ntg) * 64 + lane];
            short8 blo = blp[(kt * 8 + ntg) * 64 + lane];
#pragma unroll
            for (int rt = 0; rt < 4; rt++) {
                acc[rt][nt] = __builtin_amdgcn_mfma_f32_16x16x32_bf16(ahi[rt], bhi, acc[rt][nt], 0, 0, 0);
                acc[rt][nt] = __builtin_amdgcn_mfma_f32_16x16x32_bf16(alo[rt], bhi, acc[rt][nt], 0, 0, 0);
                acc[rt][nt] = __builtin_amdgcn_mfma_f32_16x16x32_bf16(ahi[rt], blo, acc[rt][nt], 0, 0, 0);
            }
        }
    }

    // epilogue: bias, store, banked stats (C/D layout: col=lane&15, row=quad*4+reg)
    int bank = blockIdx.x & (NBANK - 1);
#pragma unroll
    for (int nt = 0; nt < 2; nt++) {
        int col = (wid * 2 + nt) * 16 + l16;
        float bv = bias[col];
        float s = 0.f, q = 0.f;
#pragma unroll
        for (int rt = 0; rt < 4; rt++) {
#pragma unroll
            for (int v = 0; v < 4; v++) {
                int r = row0 + rt * 16 + quad * 4 + v;
                float o = acc[rt][nt][v] + bv;
                if (r < GN) {
                    s += o; q += o * o;
                    if (MODE == 1 && out_bf16) Cbf[(size_t)r * DD + col] = f2b(o);
                    else                       Cf32[(size_t)r * DD + col] = o;
                }
            }
        }
        s += __shfl_xor(s, 16); s += __shfl_xor(s, 32);
        q += __shfl_xor(q, 16); q += __shfl_xor(q, 32);
        if (lane < 16) {
            atomicAdd(&stats_out[bank * 256 + col], s);
            atomicAdd(&stats_out[bank * 256 + 128 + col], q);
        }
    }
}

// ---------------------------------------------------------------- BN2 apply, layer 4 only (f32 out)
__global__ __launch_bounds__(256) void bn_apply_kernel(
    const float* __restrict__ Z, const float* __restrict__ stats2,
    const float* __restrict__ g, const float* __restrict__ b,
    float* __restrict__ fout)
{
    __shared__ float sc_s[DD], tr_s[DD];
    int tid = threadIdx.x;
    if (tid < DD) {
        float s = 0.f, q = 0.f;
#pragma unroll
        for (int bk = 0; bk < NBANK; bk++) {
            s += stats2[bk * 256 + tid];
            q += stats2[bk * 256 + 128 + tid];
        }
        float m = s * (1.0f / GN);
        float v = q * (1.0f / GN) - m * m;
        float sc = g[tid] * rsqrtf(v + 1e-5f);
        sc_s[tid] = sc;
        tr_s[tid] = b[tid] - m * sc;
    }
    __syncthreads();
    const int total = GN * DD;
    for (int t = blockIdx.x * 256 + tid; t < total; t += gridDim.x * 256) {
        int c = t & 127;
        fout[t] = Z[t] * sc_s[c] + tr_s[c];
    }
}

// ---------------------------------------------------------------- host launcher
extern "C" void kernel_launch(void* const* d_in, const int* in_sizes, int n_in,
                              void* d_out, int out_size, void* d_ws, size_t ws_size,
                              hipStream_t stream)
{
    const int*   x        = (const int*)d_in[0];
    const int*   ei       = (const int*)d_in[1];
    const int*   eai      = (const int*)d_in[2];
    const float* eaf      = (const float*)d_in[3];
    const int*   atom_off = (const int*)d_in[4];
    const int*   bond_off = (const int*)d_in[5];
    const float* atom_emb = (const float*)d_in[6];
    const float* bond_emb = (const float*)d_in[7];
    const float* W_bl     = (const float*)d_in[8];
    const float* b_bl     = (const float*)d_in[9];
    const float* W_pr     = (const float*)d_in[10];
    const float* b_pr     = (const float*)d_in[11];
    const float* W1       = (const float*)d_in[12];
    const float* b1       = (const float*)d_in[13];
    const float* bn1g     = (const float*)d_in[14];
    const float* bn1b     = (const float*)d_in[15];
    const float* W2       = (const float*)d_in[16];
    const float* b2       = (const float*)d_in[17];
    const float* eps_gin  = (const float*)d_in[18];
    const float* bng      = (const float*)d_in[19];
    const float* bnb      = (const float*)d_in[20];
    float* out = (float*)d_out;

    char* p = (char*)d_ws;
    unsigned short* h_bf  = (unsigned short*)p;  p += (size_t)GN * DD * 2;   // atom output (layer 0)
    unsigned short* z2_bf = (unsigned short*)p;  p += (size_t)GN * DD * 2;   // raw z2 (layers 0-3)
    float* A              = (float*)p;           p += (size_t)GN * DD * 4;   // edge output
    float* z1             = (float*)p;           p += (size_t)GN * DD * 4;
    float* z2f            = (float*)p;           p += (size_t)GN * DD * 4;   // f32 z2 (layer 4)
    unsigned short* tbl_bl   = (unsigned short*)p;  p += (size_t)5 * (TQ + 1) * DD * 2;
    unsigned short* tbl_pr   = (unsigned short*)p;  p += (size_t)5 * (TQ + 1) * DD * 2;
    unsigned short* tbl_bond = (unsigned short*)p;  p += (size_t)5 * NBOND * DD * 2;
    unsigned short* wf_hi    = (unsigned short*)p;  p += (size_t)10 * 16384 * 2;
    unsigned short* wf_lo    = (unsigned short*)p;  p += (size_t)10 * 16384 * 2;
    float* stats_all = (float*)p;  p += (size_t)10 * SSET * 4;   // [layer][{1,2}][bank][256]
    int* count    = (int*)p;    p += (size_t)GN * 4;
    int* fill     = (int*)p;    p += (size_t)GN * 4;
    int* row_start= (int*)p;    p += (size_t)(GN + 1) * 4;
    int* blocksum = (int*)p;    p += (size_t)SCB * 4;
    int* blockoff = (int*)p;    p += (size_t)SCB * 4;
    p = (char*)(((size_t)p + 15) & ~(size_t)15);
    int4* ep      = (int4*)p;   p += (size_t)GE * 16;

    hipMemsetAsync(count, 0, (size_t)GN * 4, stream);
    hipMemsetAsync(fill,  0, (size_t)GN * 4, stream);
    hipMemsetAsync(stats_all, 0, (size_t)10 * SSET * 4, stream);

    hist_kernel<<<(GE + 255) / 256, 256, 0, stream>>>(ei, count);
    scan1_kernel<<<SCB, 1024, 0, stream>>>(count, row_start, blocksum);
    scan2_kernel<<<1, 64, 0, stream>>>(blocksum, blockoff);
    scan3_kernel<<<SCB, 1024, 0, stream>>>(row_start, blockoff);
    scatter_kernel<<<(GE + 255) / 256, 256, 0, stream>>>(ei, eai, eaf, row_start, fill, ep);
    atom_kernel<<<(GN * DD + 255) / 256, 256, 0, stream>>>(x, atom_off, atom_emb, h_bf);
    wfrag_kernel<<<80, 256, 0, stream>>>(W1, W2, wf_hi, wf_lo);
    tables_kernel<<<5 * TROWS, 128, 0, stream>>>(
        W_bl, b_bl, W_pr, b_pr, bond_emb, bond_off, tbl_bl, tbl_pr, tbl_bond);

    for (int l = 0; l < 5; l++) {
        float* stats1 = stats_all + (size_t)(2 * l + 0) * SSET;
        float* stats2 = stats_all + (size_t)(2 * l + 1) * SSET;
        float* stats2_prev = stats_all + (size_t)(2 * (l - 1) + 1) * SSET;

        // layer 0: hsrc = atom h (identity); layers 1-4: hsrc = raw z2 of l-1, bn2+relu on the fly
        edge_kernel<<<GN / 4, 256, 0, stream>>>(
            ep,
            tbl_bl + (size_t)l * (TQ + 1) * DD,
            tbl_pr + (size_t)l * (TQ + 1) * DD,
            tbl_bond + (size_t)l * NBOND * DD,
            (l == 0) ? h_bf : z2_bf, row_start, eps_gin, l,
            (l > 0) ? 1 : 0,
            (l > 0) ? stats2_prev : stats_all,          // unused when apply_bn=0
            bng + (size_t)(l > 0 ? l - 1 : 0) * DD,
            bnb + (size_t)(l > 0 ? l - 1 : 0) * DD,
            A);

        gemm_kernel<0><<<NB, 256, 0, stream>>>(
            A, wf_hi + (size_t)(l * 2 + 0) * 16384, wf_lo + (size_t)(l * 2 + 0) * 16384,
            b1 + (size_t)l * DD, nullptr, z1, 0,
            nullptr, nullptr, nullptr, stats1);

        gemm_kernel<1><<<NB, 256, 0, stream>>>(
            z1, wf_hi + (size_t)(l * 2 + 1) * 16384, wf_lo + (size_t)(l * 2 + 1) * 16384,
            b2 + (size_t)l * DD, z2_bf, z2f, (l < 4) ? 1 : 0,
            stats1, bn1g + (size_t)l * DD, bn1b + (size_t)l * DD, stats2);
    }

    bn_apply_kernel<<<1024, 256, 0, stream>>>(
        z2f, stats_all + (size_t)9 * SSET, bng + (size_t)4 * DD, bnb + (size_t)4 * DD, out);
}